// Round 6
// baseline (1597.180 us; speedup 1.0000x reference)
//
#include <hip/hip_runtime.h>
#include <math.h>

#define C_CLS 40
#define RPB 6   // rows per 256-thread block in scale_kernel

struct __align__(8) Edge { int c; float w; };
typedef float __attribute__((ext_vector_type(4))) f4;

// ---- runtime mask element-size handling ------------------------------------
static __device__ __forceinline__ bool load_mask(const void* p, int esz, int i) {
  if (esz == 1) return ((const unsigned char*)p)[i] != 0;
  return ((const unsigned int*)p)[i] != 0u;  // works for int32 0/1 and f32 0.0/1.0
}

__global__ void detect_kernel(const unsigned int* m, int* flag) {
  __shared__ int bad;
  if (threadIdx.x == 0) bad = 0;
  __syncthreads();
  unsigned int v = m[threadIdx.x];
  if (!(v == 0u || v == 1u || v == 0x3F800000u)) bad = 1;  // benign race
  __syncthreads();
  if (threadIdx.x == 0) flag[0] = bad ? 1 : 4;  // element size in bytes
}

// ---- CSR build: bucket counting-sort, 64 slots per bucket ------------------
// bucket = row >> 7 (128 rows); slot = blockIdx & 63. Counter idx =
// (bucket<<6)+slot => 50K counters (same atomic-address density as a plain
// per-row histogram, which measured ~70us; 8 slots = 6256 counters caused
// catastrophic cross-XCD line contention). Bucket-major layout keeps each
// bucket's 64 slot-chunks contiguous in eg2.
__global__ void countA_kernel(const int* __restrict__ row, int* __restrict__ cnt2, int E) {
  int e = blockIdx.x * 256 + threadIdx.x;
  int s = blockIdx.x & 63;
  if (e < E) atomicAdd(&cnt2[((row[e] >> 7) << 6) + s], 1);
}

// single block: exclusive scan of NB*64 counters -> cur2 (scatter cursors) and
// base[bucket] (= offset of bucket's first slot). Also rp[n]=E.
__global__ void __launch_bounds__(1024) scanA_kernel(const int* __restrict__ cnt2,
                                                     int* __restrict__ cur2,
                                                     int* __restrict__ base,
                                                     int NB, int E,
                                                     int* __restrict__ rp, int n) {
  __shared__ int sh[1024];
  const int M = NB * 64;
  const int per = (M + 1023) / 1024;
  const int t = threadIdx.x;
  const int s0 = t * per;
  int local = 0;
  for (int k = 0; k < per; ++k) {
    int idx = s0 + k;
    if (idx < M) local += cnt2[idx];
  }
  sh[t] = local;
  __syncthreads();
  for (int o = 1; o < 1024; o <<= 1) {
    int u = (t >= o) ? sh[t - o] : 0;
    __syncthreads();
    sh[t] += u;
    __syncthreads();
  }
  int run = sh[t] - local;  // exclusive
  for (int k = 0; k < per; ++k) {
    int idx = s0 + k;
    if (idx < M) {
      cur2[idx] = run;
      if ((idx & 63) == 0) base[idx >> 6] = run;
      run += cnt2[idx];
    }
  }
  if (t == 0) {
    base[NB] = E;
    rp[n] = E;
  }
}

// scatter edges into sub-bucket regions (packed: low17=col, bits17..23=row&127)
__global__ void scatA_kernel(const int* __restrict__ row, const int* __restrict__ col,
                             const float* __restrict__ w, int* __restrict__ cur2,
                             long long* __restrict__ eg2, int E) {
  int e = blockIdx.x * 256 + threadIdx.x;
  int s = blockIdx.x & 63;
  if (e < E) {
    int r = row[e];
    int pos = atomicAdd(&cur2[((r >> 7) << 6) + s], 1);
    unsigned lo = (unsigned)col[e] | ((unsigned)(r & 127) << 17);
    unsigned long long v = ((unsigned long long)__float_as_uint(w[e]) << 32) | lo;
    eg2[pos] = (long long)v;
  }
}

// one block per bucket: exact row placement (writes land in a 16KB window),
// fused rp + deg computation.
__global__ void __launch_bounds__(256) passB_kernel(const long long* __restrict__ eg2,
                                                    const int* __restrict__ base,
                                                    int* __restrict__ rp,
                                                    Edge* __restrict__ eg,
                                                    float* __restrict__ deg, int n) {
  __shared__ int lcnt[128];
  __shared__ int lofs[128];
  __shared__ float ldeg[128];
  const int b = blockIdx.x;
  const int e0 = base[b], e1 = base[b + 1];
  const int t = threadIdx.x;
  if (t < 128) { lcnt[t] = 0; ldeg[t] = 0.f; }
  __syncthreads();
  for (int e = e0 + t; e < e1; e += 256) {
    unsigned lo = (unsigned)eg2[e];
    atomicAdd(&lcnt[(lo >> 17) & 127], 1);
  }
  __syncthreads();
  if (t == 0) {
    int run = e0;
    for (int r = 0; r < 128; ++r) { lofs[r] = run; run += lcnt[r]; }
  }
  __syncthreads();
  const int rowbase = b << 7;
  if (t < 128) {
    int gi = rowbase + t;
    if (gi < n) rp[gi] = lofs[t];
    lcnt[t] = 0;  // reuse as cursor
  }
  __syncthreads();
  for (int e = e0 + t; e < e1; e += 256) {
    unsigned long long v = (unsigned long long)eg2[e];
    unsigned lo = (unsigned)v;
    int r = (lo >> 17) & 127;
    Edge ed;
    ed.c = (int)(lo & 0x1FFFFu);
    ed.w = __uint_as_float((unsigned)(v >> 32));
    int pos = lofs[r] + atomicAdd(&lcnt[r], 1);
    eg[pos] = ed;
    atomicAdd(&ldeg[r], ed.w);
  }
  __syncthreads();
  if (t < 128) {
    int gi = rowbase + t;
    if (gi < n) deg[gi] = ldeg[t];
  }
}

__global__ void rsqrt_kernel(float* deg, int n) {
  int i = blockIdx.x * blockDim.x + threadIdx.x;
  if (i < n) {
    float d = deg[i];
    deg[i] = (d > 0.f) ? rsqrtf(d) : 0.f;  // deg becomes dis
  }
}

// eg[e].w = dis[r] * w * dis[c], in place (each edge owned by exactly one row).
__global__ void norm_kernel(Edge* __restrict__ eg, const int* __restrict__ rp,
                            const float* __restrict__ dis, int n) {
  int i = blockIdx.x * blockDim.x + threadIdx.x;
  if (i < n) {
    float dr = dis[i];
    int e1 = rp[i + 1];
    for (int e = rp[i]; e < e1; ++e) {
      Edge ed = eg[e];
      ed.w = dr * ed.w * dis[ed.c];
      eg[e] = ed;
    }
  }
}

// ---- error init + sigma numerator + mask count (fused, grid-stride) --------
__global__ void __launch_bounds__(256) init_error_kernel(
    float4* __restrict__ x4, const float4* __restrict__ ysoft4,
    const int* __restrict__ ytrue, const void* maskp,
    const int* __restrict__ flag, float* __restrict__ sig,
    int* __restrict__ numel, int n) {
  const int esz = flag[0];
  const int total = n * 10;  // quads
  float asum = 0.f;
  int cnt = 0;
  for (int q = blockIdx.x * blockDim.x + threadIdx.x; q < total;
       q += gridDim.x * blockDim.x) {
    int i = q / 10;
    int c4 = q - i * 10;
    float4 e = make_float4(0.f, 0.f, 0.f, 0.f);
    if (load_mask(maskp, esz, i)) {
      float4 p = ysoft4[q];
      int t = ytrue[i];
      int cb = c4 * 4;
      e.x = ((t == cb) ? 1.f : 0.f) - p.x;
      e.y = ((t == cb + 1) ? 1.f : 0.f) - p.y;
      e.z = ((t == cb + 2) ? 1.f : 0.f) - p.z;
      e.w = ((t == cb + 3) ? 1.f : 0.f) - p.w;
      if (c4 == 0) cnt++;
    }
    x4[q] = e;
    asum += fabsf(e.x) + fabsf(e.y) + fabsf(e.z) + fabsf(e.w);
  }
  for (int o = 32; o > 0; o >>= 1) {
    asum += __shfl_down(asum, o);
    cnt += __shfl_down(cnt, o);
  }
  __shared__ float swf[4];
  __shared__ int swi[4];
  int lane = threadIdx.x & 63, wv = threadIdx.x >> 6;
  if (lane == 0) { swf[wv] = asum; swi[wv] = cnt; }
  __syncthreads();
  if (threadIdx.x == 0) {
    atomicAdd(sig, swf[0] + swf[1] + swf[2] + swf[3]);
    atomicAdd(numel, swi[0] + swi[1] + swi[2] + swi[3]);
  }
}

// ---- propagation step: POST 0 = clip[-1,1], 1 = row softmax ----------------
// 10 lanes per row, float4 per lane; block = 320 threads = 32 rows exactly.
// Edge stream: nontemporal loads; output: nontemporal stores (protect L2 for x).
static __device__ __forceinline__ Edge nt_edge(const Edge* p) {
  unsigned long long v = (unsigned long long)__builtin_nontemporal_load((const long long*)p);
  Edge ed;
  ed.c = (int)(unsigned)v;
  ed.w = __uint_as_float((unsigned)(v >> 32));
  return ed;
}

template <int POST>
__global__ void __launch_bounds__(320) prop_step(const float* __restrict__ xin,
                                                 float* __restrict__ xout,
                                                 const int* __restrict__ rp,
                                                 const Edge* __restrict__ eg,
                                                 float alpha, int n) {
  const int t = threadIdx.x;
  const int lr = t / 10;       // 0..31
  const int c4 = t - lr * 10;  // 0..9
  const int i = blockIdx.x * 32 + lr;
  const bool active = (i < n);
  const float4* __restrict__ X4 = (const float4*)xin;
  float4 v = make_float4(0.f, 0.f, 0.f, 0.f);
  if (active) {
    int e0 = rp[i], e1 = rp[i + 1];
    float4 self = X4[i * 10 + c4];
    float4 acc = make_float4(0.f, 0.f, 0.f, 0.f);
    int e = e0;
    for (; e + 3 < e1; e += 4) {  // 4 outstanding gathers
      Edge d0 = nt_edge(&eg[e]), d1 = nt_edge(&eg[e + 1]),
           d2 = nt_edge(&eg[e + 2]), d3 = nt_edge(&eg[e + 3]);
      float4 x0 = X4[d0.c * 10 + c4];
      float4 x1 = X4[d1.c * 10 + c4];
      float4 x2 = X4[d2.c * 10 + c4];
      float4 x3 = X4[d3.c * 10 + c4];
      acc.x = fmaf(d0.w, x0.x, acc.x); acc.y = fmaf(d0.w, x0.y, acc.y);
      acc.z = fmaf(d0.w, x0.z, acc.z); acc.w = fmaf(d0.w, x0.w, acc.w);
      acc.x = fmaf(d1.w, x1.x, acc.x); acc.y = fmaf(d1.w, x1.y, acc.y);
      acc.z = fmaf(d1.w, x1.z, acc.z); acc.w = fmaf(d1.w, x1.w, acc.w);
      acc.x = fmaf(d2.w, x2.x, acc.x); acc.y = fmaf(d2.w, x2.y, acc.y);
      acc.z = fmaf(d2.w, x2.z, acc.z); acc.w = fmaf(d2.w, x2.w, acc.w);
      acc.x = fmaf(d3.w, x3.x, acc.x); acc.y = fmaf(d3.w, x3.y, acc.y);
      acc.z = fmaf(d3.w, x3.z, acc.z); acc.w = fmaf(d3.w, x3.w, acc.w);
    }
    for (; e < e1; ++e) {
      Edge d = nt_edge(&eg[e]);
      float4 xv = X4[d.c * 10 + c4];
      acc.x = fmaf(d.w, xv.x, acc.x); acc.y = fmaf(d.w, xv.y, acc.y);
      acc.z = fmaf(d.w, xv.z, acc.z); acc.w = fmaf(d.w, xv.w, acc.w);
    }
    float beta = 1.f - alpha;
    v.x = alpha * acc.x + beta * self.x;
    v.y = alpha * acc.y + beta * self.y;
    v.z = alpha * acc.z + beta * self.z;
    v.w = alpha * acc.w + beta * self.w;
  }
  if (POST == 0) {
    if (active) {
      f4 o = {fminf(1.f, fmaxf(-1.f, v.x)), fminf(1.f, fmaxf(-1.f, v.y)),
              fminf(1.f, fmaxf(-1.f, v.z)), fminf(1.f, fmaxf(-1.f, v.w))};
      __builtin_nontemporal_store(o, &((f4*)xout)[i * 10 + c4]);
    }
  } else {
    __shared__ float sh[32][10];
    __shared__ float shr[32];
    float lmax = fmaxf(fmaxf(v.x, v.y), fmaxf(v.z, v.w));
    if (active) sh[lr][c4] = lmax;
    __syncthreads();
    if (active && c4 == 0) {
      float m = sh[lr][0];
#pragma unroll
      for (int k = 1; k < 10; ++k) m = fmaxf(m, sh[lr][k]);
      shr[lr] = m;
    }
    __syncthreads();
    float m = active ? shr[lr] : 0.f;
    float ex = __expf(v.x - m), ey = __expf(v.y - m),
          ez = __expf(v.z - m), ew = __expf(v.w - m);
    if (active) sh[lr][c4] = ex + ey + ez + ew;
    __syncthreads();
    if (active && c4 == 0) {
      float s = sh[lr][0];
#pragma unroll
      for (int k = 1; k < 10; ++k) s += sh[lr][k];
      shr[lr] = s;
    }
    __syncthreads();
    if (active) {
      float inv = 1.f / shr[lr];
      f4 o = {ex * inv, ey * inv, ez * inv, ew * inv};
      __builtin_nontemporal_store(o, &((f4*)xout)[i * 10 + c4]);
    }
  }
}

// ---- scale + y_s -----------------------------------------------------------
__global__ void __launch_bounds__(256) scale_kernel(const float* __restrict__ sm,
                                                    float* __restrict__ out,
                                                    const float* __restrict__ ysoft,
                                                    const int* __restrict__ ytrue,
                                                    const void* maskp,
                                                    const int* __restrict__ flag,
                                                    const float* __restrict__ sig,
                                                    const int* __restrict__ numel, int n) {
  int t = threadIdx.x;
  int lr = t / C_CLS, c = t - lr * C_CLS;
  int i = blockIdx.x * RPB + lr;
  bool active = (lr < RPB) && (i < n);
  __shared__ float sh[RPB][C_CLS];
  __shared__ float shd[RPB];
  float v = 0.f;
  if (active) {
    v = sm[i * C_CLS + c];
    sh[lr][c] = fabsf(v);
  }
  __syncthreads();
  if (active && c == 0) {
    float d = 0.f;
#pragma unroll
    for (int k = 0; k < C_CLS; ++k) d += sh[lr][k];
    shd[lr] = d;
  }
  __syncthreads();
  if (active) {
    float denom = shd[lr];
    float sigma = sig[0] / (float)numel[0];
    float raw = sigma / ((denom > 0.f) ? denom : 1.f);
    float scale = (denom <= 0.f || raw > 1000.f) ? 1.f : raw;
    float yc = ysoft[i * C_CLS + c] + scale * v;
    float oh = (ytrue[i] == c) ? 1.f : 0.f;
    out[i * C_CLS + c] = load_mask(maskp, flag[0], i) ? oh : yc;
  }
}

// ---- launch ---------------------------------------------------------------
extern "C" void kernel_launch(void* const* d_in, const int* in_sizes, int n_in,
                              void* d_out, int out_size, void* d_ws, size_t ws_size,
                              hipStream_t stream) {
  const int* y_true = (const int*)d_in[0];
  const float* y_soft = (const float*)d_in[1];
  const void* maskp = d_in[2];
  const int* ei = (const int*)d_in[3];
  const float* ew = (const float*)d_in[4];
  const int n = in_sizes[0];
  const int E = in_sizes[4];
  const int* row = ei;
  const int* col = ei + E;
  const int NB = (n + 127) >> 7;  // row buckets of 128

  char* ws = (char*)d_ws;
  size_t o = 0;
  auto alloc = [&](size_t bytes) -> void* {
    void* p = ws + o;
    o += (bytes + 255) & ~(size_t)255;
    return p;
  };
  float* xA = (float*)alloc((size_t)n * C_CLS * 4);  // also aliased as eg2 during build
  Edge* eg = (Edge*)alloc((size_t)E * 8);
  float* dis = (float*)alloc((size_t)n * 4);  // deg then rsqrt in place
  float* sig = (float*)alloc(4);
  int* numel = (int*)alloc(4);
  int* flag = (int*)alloc(4);
  int* rp = (int*)alloc((size_t)(n + 1) * 4);
  int* cnt2 = (int*)alloc((size_t)NB * 64 * 4);
  int* cur2 = (int*)alloc((size_t)NB * 64 * 4);
  int* base = (int*)alloc((size_t)(NB + 1) * 4);
  long long* eg2 = (long long*)xA;  // E*8 = 12.8MB <= n*160B = 16MB
  float* xB = (float*)d_out;        // d_out doubles as ping-pong buffer

  hipMemsetAsync(cnt2, 0, (size_t)NB * 64 * 4, stream);
  hipMemsetAsync(sig, 0, 4, stream);
  hipMemsetAsync(numel, 0, 4, stream);

  const int be = (E + 255) / 256;
  const int bn = (n + 255) / 256;
  const int bp = (n + 31) / 32;         // prop_step blocks (320 thr, 32 rows)
  const int bsc = (n + RPB - 1) / RPB;  // scale_kernel blocks

  detect_kernel<<<1, 256, 0, stream>>>((const unsigned int*)maskp, flag);
  countA_kernel<<<be, 256, 0, stream>>>(row, cnt2, E);
  scanA_kernel<<<1, 1024, 0, stream>>>(cnt2, cur2, base, NB, E, rp, n);
  scatA_kernel<<<be, 256, 0, stream>>>(row, col, ew, cur2, eg2, E);
  passB_kernel<<<NB, 256, 0, stream>>>(eg2, base, rp, eg, dis, n);
  rsqrt_kernel<<<bn, 256, 0, stream>>>(dis, n);
  norm_kernel<<<bn, 256, 0, stream>>>(eg, rp, dis, n);
  init_error_kernel<<<512, 256, 0, stream>>>((float4*)xA, (const float4*)y_soft,
                                             y_true, maskp, flag, sig, numel, n);

  // Phase 1: correct (alpha=0.9, clip). Start a=xA -> after 10 steps result in xA.
  float* a = xA;
  float* b = xB;
  for (int k = 0; k < 10; ++k) {
    prop_step<0><<<bp, 320, 0, stream>>>(a, b, rp, eg, 0.9f, n);
    float* t = a; a = b; b = t;
  }
  // a == xA (smoothed error). Scale + y_s written into d_out.
  scale_kernel<<<bsc, 256, 0, stream>>>(a, b, y_soft, y_true, maskp, flag, sig, numel, n);
  { float* t = a; a = b; b = t; }  // a = d_out (y_s), b = xA

  // Phase 2: smooth (alpha=0.8, softmax). 10 steps starting at d_out -> ends in d_out.
  for (int k = 0; k < 10; ++k) {
    prop_step<1><<<bp, 320, 0, stream>>>(a, b, rp, eg, 0.8f, n);
    float* t = a; a = b; b = t;
  }
}

// Round 7
// 1405.279 us; speedup vs baseline: 1.1366x; 1.1366x over previous
//
#include <hip/hip_runtime.h>
#include <math.h>

#define C_CLS 40
#define RPB 6   // rows per 256-thread block in scale_kernel

struct __align__(8) Edge { int c; float w; };

// ---- runtime mask element-size handling ------------------------------------
static __device__ __forceinline__ bool load_mask(const void* p, int esz, int i) {
  if (esz == 1) return ((const unsigned char*)p)[i] != 0;
  return ((const unsigned int*)p)[i] != 0u;  // works for int32 0/1 and f32 0.0/1.0
}

__global__ void detect_kernel(const unsigned int* m, int* flag) {
  __shared__ int bad;
  if (threadIdx.x == 0) bad = 0;
  __syncthreads();
  unsigned int v = m[threadIdx.x];
  if (!(v == 0u || v == 1u || v == 0x3F800000u)) bad = 1;  // benign race
  __syncthreads();
  if (threadIdx.x == 0) flag[0] = bad ? 1 : 4;  // element size in bytes
}

// ---- CSR build (simple, proven) --------------------------------------------
__global__ void hist_kernel(const int* __restrict__ row, int* __restrict__ cnt, int E) {
  int e = blockIdx.x * blockDim.x + threadIdx.x;
  if (e < E) atomicAdd(&cnt[row[e]], 1);
}

__global__ void scan1_kernel(const int* __restrict__ cnt, int* __restrict__ rp,
                             int* __restrict__ part, int n) {
  __shared__ int sh[256];
  int gid = blockIdx.x * 256 + threadIdx.x;
  int v = (gid < n) ? cnt[gid] : 0;
  sh[threadIdx.x] = v;
  __syncthreads();
  for (int o = 1; o < 256; o <<= 1) {
    int t = (threadIdx.x >= o) ? sh[threadIdx.x - o] : 0;
    __syncthreads();
    sh[threadIdx.x] += t;
    __syncthreads();
  }
  if (gid < n) rp[gid] = sh[threadIdx.x] - v;  // exclusive within block
  if (threadIdx.x == 255) part[blockIdx.x] = sh[255];
}

__global__ void scan2_kernel(int* part, int B) {
  __shared__ int sh[1024];
  int t = threadIdx.x;
  int v = (t < B) ? part[t] : 0;
  sh[t] = v;
  __syncthreads();
  for (int o = 1; o < 1024; o <<= 1) {
    int u = (t >= o) ? sh[t - o] : 0;
    __syncthreads();
    sh[t] += u;
    __syncthreads();
  }
  if (t < B) part[t] = sh[t] - v;  // exclusive block offsets
}

__global__ void scan3_kernel(int* __restrict__ rp, int* __restrict__ cur,
                             const int* __restrict__ part, int n, int E) {
  int gid = blockIdx.x * 256 + threadIdx.x;
  if (gid < n) {
    int v = rp[gid] + part[blockIdx.x];
    rp[gid] = v;
    cur[gid] = v;
  }
  if (gid == 0) rp[n] = E;
}

__global__ void scatter_kernel(const int* __restrict__ row, const int* __restrict__ col,
                               const float* __restrict__ w,
                               int* __restrict__ cursor, Edge* __restrict__ eg, int E) {
  int e = blockIdx.x * blockDim.x + threadIdx.x;
  if (e < E) {
    int r = row[e];
    int pos = atomicAdd(&cursor[r], 1);
    Edge ed;
    ed.c = col[e];
    ed.w = w[e];
    eg[pos] = ed;
  }
}

// deg[i] = sum of raw w over row i's CSR segment; dis[i] = rsqrt(deg) (fused).
__global__ void deg_rsqrt_kernel(const Edge* __restrict__ eg, const int* __restrict__ rp,
                                 float* __restrict__ dis, int n) {
  int i = blockIdx.x * blockDim.x + threadIdx.x;
  if (i < n) {
    float s = 0.f;
    int e1 = rp[i + 1];
    for (int e = rp[i]; e < e1; ++e) s += eg[e].w;
    dis[i] = (s > 0.f) ? rsqrtf(s) : 0.f;
  }
}

// eg[e].w = dis[r] * w * dis[c], in place (each edge owned by exactly one row).
__global__ void norm_kernel(Edge* __restrict__ eg, const int* __restrict__ rp,
                            const float* __restrict__ dis, int n) {
  int i = blockIdx.x * blockDim.x + threadIdx.x;
  if (i < n) {
    float dr = dis[i];
    int e1 = rp[i + 1];
    for (int e = rp[i]; e < e1; ++e) {
      Edge ed = eg[e];
      ed.w = dr * ed.w * dis[ed.c];
      eg[e] = ed;
    }
  }
}

// ---- error init + sigma numerator + mask count (fused, grid-stride) --------
__global__ void __launch_bounds__(256) init_error_kernel(
    float4* __restrict__ x4, const float4* __restrict__ ysoft4,
    const int* __restrict__ ytrue, const void* maskp,
    const int* __restrict__ flag, float* __restrict__ sig,
    int* __restrict__ numel, int n) {
  const int esz = flag[0];
  const int total = n * 10;  // quads
  float asum = 0.f;
  int cnt = 0;
  for (int q = blockIdx.x * blockDim.x + threadIdx.x; q < total;
       q += gridDim.x * blockDim.x) {
    int i = q / 10;
    int c4 = q - i * 10;
    float4 e = make_float4(0.f, 0.f, 0.f, 0.f);
    if (load_mask(maskp, esz, i)) {
      float4 p = ysoft4[q];
      int t = ytrue[i];
      int cb = c4 * 4;
      e.x = ((t == cb) ? 1.f : 0.f) - p.x;
      e.y = ((t == cb + 1) ? 1.f : 0.f) - p.y;
      e.z = ((t == cb + 2) ? 1.f : 0.f) - p.z;
      e.w = ((t == cb + 3) ? 1.f : 0.f) - p.w;
      if (c4 == 0) cnt++;
    }
    x4[q] = e;
    asum += fabsf(e.x) + fabsf(e.y) + fabsf(e.z) + fabsf(e.w);
  }
  for (int o = 32; o > 0; o >>= 1) {
    asum += __shfl_down(asum, o);
    cnt += __shfl_down(cnt, o);
  }
  __shared__ float swf[4];
  __shared__ int swi[4];
  int lane = threadIdx.x & 63, wv = threadIdx.x >> 6;
  if (lane == 0) { swf[wv] = asum; swi[wv] = cnt; }
  __syncthreads();
  if (threadIdx.x == 0) {
    atomicAdd(sig, swf[0] + swf[1] + swf[2] + swf[3]);
    atomicAdd(numel, swi[0] + swi[1] + swi[2] + swi[3]);
  }
}

// ---- propagation step: POST 0 = clip[-1,1], 1 = row softmax ----------------
// 10 lanes per row, float4 per lane; block = 320 threads = 32 rows exactly.
template <int POST>
__global__ void __launch_bounds__(320) prop_step(const float* __restrict__ xin,
                                                 float* __restrict__ xout,
                                                 const int* __restrict__ rp,
                                                 const Edge* __restrict__ eg,
                                                 float alpha, int n) {
  const int t = threadIdx.x;
  const int lr = t / 10;       // 0..31
  const int c4 = t - lr * 10;  // 0..9
  const int i = blockIdx.x * 32 + lr;
  const bool active = (i < n);
  const float4* __restrict__ X4 = (const float4*)xin;
  float4 v = make_float4(0.f, 0.f, 0.f, 0.f);
  if (active) {
    int e0 = rp[i], e1 = rp[i + 1];
    float4 self = X4[i * 10 + c4];
    float4 acc = make_float4(0.f, 0.f, 0.f, 0.f);
    int e = e0;
    for (; e + 3 < e1; e += 4) {  // 4 outstanding gathers
      Edge d0 = eg[e], d1 = eg[e + 1], d2 = eg[e + 2], d3 = eg[e + 3];
      float4 x0 = X4[d0.c * 10 + c4];
      float4 x1 = X4[d1.c * 10 + c4];
      float4 x2 = X4[d2.c * 10 + c4];
      float4 x3 = X4[d3.c * 10 + c4];
      acc.x = fmaf(d0.w, x0.x, acc.x); acc.y = fmaf(d0.w, x0.y, acc.y);
      acc.z = fmaf(d0.w, x0.z, acc.z); acc.w = fmaf(d0.w, x0.w, acc.w);
      acc.x = fmaf(d1.w, x1.x, acc.x); acc.y = fmaf(d1.w, x1.y, acc.y);
      acc.z = fmaf(d1.w, x1.z, acc.z); acc.w = fmaf(d1.w, x1.w, acc.w);
      acc.x = fmaf(d2.w, x2.x, acc.x); acc.y = fmaf(d2.w, x2.y, acc.y);
      acc.z = fmaf(d2.w, x2.z, acc.z); acc.w = fmaf(d2.w, x2.w, acc.w);
      acc.x = fmaf(d3.w, x3.x, acc.x); acc.y = fmaf(d3.w, x3.y, acc.y);
      acc.z = fmaf(d3.w, x3.z, acc.z); acc.w = fmaf(d3.w, x3.w, acc.w);
    }
    for (; e < e1; ++e) {
      Edge d = eg[e];
      float4 xv = X4[d.c * 10 + c4];
      acc.x = fmaf(d.w, xv.x, acc.x); acc.y = fmaf(d.w, xv.y, acc.y);
      acc.z = fmaf(d.w, xv.z, acc.z); acc.w = fmaf(d.w, xv.w, acc.w);
    }
    float beta = 1.f - alpha;
    v.x = alpha * acc.x + beta * self.x;
    v.y = alpha * acc.y + beta * self.y;
    v.z = alpha * acc.z + beta * self.z;
    v.w = alpha * acc.w + beta * self.w;
  }
  if (POST == 0) {
    if (active) {
      float4 o;
      o.x = fminf(1.f, fmaxf(-1.f, v.x));
      o.y = fminf(1.f, fmaxf(-1.f, v.y));
      o.z = fminf(1.f, fmaxf(-1.f, v.z));
      o.w = fminf(1.f, fmaxf(-1.f, v.w));
      ((float4*)xout)[i * 10 + c4] = o;
    }
  } else {
    __shared__ float sh[32][10];
    __shared__ float shr[32];
    float lmax = fmaxf(fmaxf(v.x, v.y), fmaxf(v.z, v.w));
    if (active) sh[lr][c4] = lmax;
    __syncthreads();
    if (active && c4 == 0) {
      float m = sh[lr][0];
#pragma unroll
      for (int k = 1; k < 10; ++k) m = fmaxf(m, sh[lr][k]);
      shr[lr] = m;
    }
    __syncthreads();
    float m = active ? shr[lr] : 0.f;
    float ex = __expf(v.x - m), ey = __expf(v.y - m),
          ez = __expf(v.z - m), ew = __expf(v.w - m);
    if (active) sh[lr][c4] = ex + ey + ez + ew;
    __syncthreads();
    if (active && c4 == 0) {
      float s = sh[lr][0];
#pragma unroll
      for (int k = 1; k < 10; ++k) s += sh[lr][k];
      shr[lr] = s;
    }
    __syncthreads();
    if (active) {
      float inv = 1.f / shr[lr];
      ((float4*)xout)[i * 10 + c4] = make_float4(ex * inv, ey * inv, ez * inv, ew * inv);
    }
  }
}

// ---- scale + y_s -----------------------------------------------------------
__global__ void __launch_bounds__(256) scale_kernel(const float* __restrict__ sm,
                                                    float* __restrict__ out,
                                                    const float* __restrict__ ysoft,
                                                    const int* __restrict__ ytrue,
                                                    const void* maskp,
                                                    const int* __restrict__ flag,
                                                    const float* __restrict__ sig,
                                                    const int* __restrict__ numel, int n) {
  int t = threadIdx.x;
  int lr = t / C_CLS, c = t - lr * C_CLS;
  int i = blockIdx.x * RPB + lr;
  bool active = (lr < RPB) && (i < n);
  __shared__ float sh[RPB][C_CLS];
  __shared__ float shd[RPB];
  float v = 0.f;
  if (active) {
    v = sm[i * C_CLS + c];
    sh[lr][c] = fabsf(v);
  }
  __syncthreads();
  if (active && c == 0) {
    float d = 0.f;
#pragma unroll
    for (int k = 0; k < C_CLS; ++k) d += sh[lr][k];
    shd[lr] = d;
  }
  __syncthreads();
  if (active) {
    float denom = shd[lr];
    float sigma = sig[0] / (float)numel[0];
    float raw = sigma / ((denom > 0.f) ? denom : 1.f);
    float scale = (denom <= 0.f || raw > 1000.f) ? 1.f : raw;
    float yc = ysoft[i * C_CLS + c] + scale * v;
    float oh = (ytrue[i] == c) ? 1.f : 0.f;
    out[i * C_CLS + c] = load_mask(maskp, flag[0], i) ? oh : yc;
  }
}

// ---- launch ---------------------------------------------------------------
extern "C" void kernel_launch(void* const* d_in, const int* in_sizes, int n_in,
                              void* d_out, int out_size, void* d_ws, size_t ws_size,
                              hipStream_t stream) {
  const int* y_true = (const int*)d_in[0];
  const float* y_soft = (const float*)d_in[1];
  const void* maskp = d_in[2];
  const int* ei = (const int*)d_in[3];
  const float* ew = (const float*)d_in[4];
  const int n = in_sizes[0];
  const int E = in_sizes[4];
  const int* row = ei;
  const int* col = ei + E;

  char* ws = (char*)d_ws;
  size_t o = 0;
  auto alloc = [&](size_t bytes) -> void* {
    void* p = ws + o;
    o += (bytes + 255) & ~(size_t)255;
    return p;
  };
  float* xA = (float*)alloc((size_t)n * C_CLS * 4);
  Edge* eg = (Edge*)alloc((size_t)E * 8);
  float* dis = (float*)alloc((size_t)n * 4);
  int* cnt = (int*)alloc((size_t)n * 4);
  float* sig = (float*)alloc(4);
  int* numel = (int*)alloc(4);
  int* flag = (int*)alloc(4);
  int* rp = (int*)alloc((size_t)(n + 1) * 4);
  int* cur = (int*)alloc((size_t)n * 4);
  int* part = (int*)alloc(4096);
  float* xB = (float*)d_out;  // d_out doubles as ping-pong buffer

  hipMemsetAsync(cnt, 0, (size_t)n * 4, stream);
  hipMemsetAsync(sig, 0, 4, stream);
  hipMemsetAsync(numel, 0, 4, stream);

  const int be = (E + 255) / 256;
  const int bn = (n + 255) / 256;
  const int bp = (n + 31) / 32;         // prop_step blocks (320 thr, 32 rows)
  const int bsc = (n + RPB - 1) / RPB;  // scale_kernel blocks

  detect_kernel<<<1, 256, 0, stream>>>((const unsigned int*)maskp, flag);
  hist_kernel<<<be, 256, 0, stream>>>(row, cnt, E);
  scan1_kernel<<<bn, 256, 0, stream>>>(cnt, rp, part, n);
  scan2_kernel<<<1, 1024, 0, stream>>>(part, bn);
  scan3_kernel<<<bn, 256, 0, stream>>>(rp, cur, part, n, E);
  scatter_kernel<<<be, 256, 0, stream>>>(row, col, ew, cur, eg, E);
  deg_rsqrt_kernel<<<bn, 256, 0, stream>>>(eg, rp, dis, n);
  norm_kernel<<<bn, 256, 0, stream>>>(eg, rp, dis, n);
  init_error_kernel<<<512, 256, 0, stream>>>((float4*)xA, (const float4*)y_soft,
                                             y_true, maskp, flag, sig, numel, n);

  // Phase 1: correct (alpha=0.9, clip). Start a=xA -> after 10 steps result in xA.
  float* a = xA;
  float* b = xB;
  for (int k = 0; k < 10; ++k) {
    prop_step<0><<<bp, 320, 0, stream>>>(a, b, rp, eg, 0.9f, n);
    float* t = a; a = b; b = t;
  }
  // a == xA (smoothed error). Scale + y_s written into d_out.
  scale_kernel<<<bsc, 256, 0, stream>>>(a, b, y_soft, y_true, maskp, flag, sig, numel, n);
  { float* t = a; a = b; b = t; }  // a = d_out (y_s), b = xA

  // Phase 2: smooth (alpha=0.8, softmax). 10 steps starting at d_out -> ends in d_out.
  for (int k = 0; k < 10; ++k) {
    prop_step<1><<<bp, 320, 0, stream>>>(a, b, rp, eg, 0.8f, n);
    float* t = a; a = b; b = t;
  }
}